// Round 8
// baseline (242.984 us; speedup 1.0000x reference)
//
#include <hip/hip_runtime.h>
#include <hip/hip_bf16.h>

// R13: latency attack on attn + dead-work removal.
//  - host dtype dispatch via in_sizes[0] byte-size (bf16=2NE, fp32=4NE,
//    else ambiguous -> device-detect fallback). bf16 world: convert launch
//    skipped entirely, detect scans replaced by a constant.
//  - attn3: K staged via global_load_lds with pre-swizzled SOURCE (same
//    rule-21 pattern as proj; layout proven identical to the verified
//    ds_write path), -2 global loads -2 ds_writes/thread/tile, -8 VGPR.
//    K-DMA issued FIRST so the compiler's vmcnt(0) on V registers before
//    v_write retires it (in-order VMEM retirement) -> race-free by the
//    verified single-barrier dbuf argument.
//  - attn3: tree-structured pmax/sum (depth 5 vs 33-deep serial chains).
// R12 post-mortem: counted-vmcnt on 2-barrier 128^2 proj bought ~11us;
// attn 72->82 cross-round noise erased it. attn is latency-bound (occ 19%).

#define B_ 2
#define S_ 2048
#define D_ 1024
#define H_ 16
#define HD_ 64
#define NE_ (B_ * S_ * D_)  // 4194304
#define WN_ (D_ * D_)       // 1048576

typedef unsigned short u16;
typedef unsigned int u32;
typedef u16 __attribute__((may_alias)) u16_ma;
typedef float __attribute__((may_alias)) f32_ma;
typedef u32 v4u __attribute__((ext_vector_type(4)));
typedef v4u __attribute__((may_alias)) v4u_ma;
typedef short bf16x8 __attribute__((ext_vector_type(8)));
typedef bf16x8 __attribute__((may_alias)) bf16x8_ma;
typedef float f32x4 __attribute__((ext_vector_type(4)));
typedef float f32x16 __attribute__((ext_vector_type(16)));

__device__ __forceinline__ float bf2f(u16 u) {
  u32 x = ((u32)u) << 16;
  return __builtin_bit_cast(float, x);
}
// Software RNE f32->bf16 (harness-verified numerics, R5-R12).
__device__ __forceinline__ u16 f2bf(float f) {
  __hip_bfloat16 h = __float2bfloat16(f);
  return __builtin_bit_cast(u16, h);
}
// Raw RNE, valid for non-NaN inputs (bit-identical to f2bf there).
__device__ __forceinline__ u16 rne1(float f) {
  u32 a = __builtin_bit_cast(u32, f);
  a += 0x7FFFu + ((a >> 16) & 1u);
  return (u16)(a >> 16);
}
__device__ __forceinline__ u32 rne_pair(float lo, float hi) {
  u32 a = __builtin_bit_cast(u32, lo);
  u32 b = __builtin_bit_cast(u32, hi);
  a += 0x7FFFu + ((a >> 16) & 1u);
  b += 0x7FFFu + ((b >> 16) & 1u);
  return (a >> 16) | (b & 0xFFFF0000u);
}
__device__ __forceinline__ u32 pk2(u32 alo, u32 ahi) {
  return (u32)f2bf(__builtin_bit_cast(float, alo)) |
         ((u32)f2bf(__builtin_bit_cast(float, ahi)) << 16);
}

// async global->LDS, 16B/lane; dest = wave-uniform base + lane*16 (m104).
__device__ __forceinline__ void gl_lds16(const void* g, u16* l) {
  auto gp = (const __attribute__((address_space(1))) unsigned int*)g;
  auto lp = (__attribute__((address_space(3))) unsigned int*)(void*)l;
  __builtin_amdgcn_global_load_lds(gp, lp, 16, 0, 0);
}

// Input dtype detect (R5-R12 harness-verified). Only used in mode==2.
__device__ __forceinline__ bool detect_f32(const u16* Wg) {
  const int lane = threadIdx.x & 63;
  bool hit = false;
#pragma unroll
  for (int i = 0; i < 4; ++i) {
    v4u u = *(const v4u_ma*)(Wg + lane * 32 + i * 8);
#pragma unroll
    for (int j = 0; j < 4; ++j) {
      u32 w = u[j];
      hit |= (((w >> 7) & 0xFFu) >= 0xF0u) || (((w >> 23) & 0xFFu) >= 0xF0u);
    }
  }
  return __any(hit);
}

// ---------------------------------------------------------------------------
// Convert inputs to bf16 scratch — only in the fp32 world.
// mode: 1 = fp32 (convert), 2 = ambiguous (device detect). (mode 0 never
// launched.)
// ---------------------------------------------------------------------------
__global__ __launch_bounds__(256) void convert_bf16(
    const void* s0, const void* s1, const void* s2, const void* s3,
    const void* s4, const void* s5, const void* s6, u16* __restrict__ dst_in,
    u16* __restrict__ dst_w, const u16* __restrict__ Wdet, int mode) {
  const bool det = (mode == 1) ? true : detect_f32(Wdet);
  if (!det) return;
  const int y = blockIdx.y;
  const void* src;
  u16* dst;
  int n;
  if (y < 3) {
    src = (y == 0) ? s0 : ((y == 1) ? s1 : s2);
    dst = dst_in + (size_t)y * NE_;
    n = NE_;
  } else {
    src = (y == 3) ? s3 : ((y == 4) ? s4 : ((y == 5) ? s5 : s6));
    dst = dst_w + (size_t)(y - 3) * WN_;
    n = WN_;
  }
  const int i = (blockIdx.x * 256 + threadIdx.x) * 8;
  if (i >= n) return;
  const v4u_ma* fp = (const v4u_ma*)((const float*)src + i);
  v4u f0 = fp[0], f1 = fp[1];
  v4u out;
  out[0] = pk2(f0[0], f0[1]);
  out[1] = pk2(f0[2], f0[3]);
  out[2] = pk2(f1[0], f1[1]);
  out[3] = pk2(f1[2], f1[3]);
  *(v4u_ma*)(dst + i) = out;
}

// ---------------------------------------------------------------------------
// C[4096,1024] = A @ W^T, all-bf16. BM=128, BK=64, BN templated.
// LDS double-buffer + counted vmcnt (R12-verified). mode selects source:
// 0 = original d_in (bf16 bits), 1 = converted scratch, 2 = device detect.
// z==0 folds exact 1/sqrt(HD)=0.125 into Q.
// ---------------------------------------------------------------------------
template <int BN, bool OUT_DET>
__global__ __launch_bounds__(256) void proj_g(
    const u16* __restrict__ Asc, const u16* __restrict__ Wsc,
    void* __restrict__ Cb, const u16* __restrict__ Wdet,
    const u16* __restrict__ Ao0, const u16* __restrict__ Ao1,
    const u16* __restrict__ Ao2, const u16* __restrict__ Wo0,
    const u16* __restrict__ Wo1, const u16* __restrict__ Wo2, int mode) {
  __shared__ u16 Al[2][128 * 64];
  __shared__ u16 Wl[2][BN * 64];

  const bool det = (mode == 1) ? true : ((mode == 0) ? false : detect_f32(Wdet));
  const int z = blockIdx.z;

  const u16* Aptr;
  const u16* Wptr;
  if (OUT_DET) {
    Aptr = Asc;  // attn output: always bf16 scratch
    Wptr = det ? Wsc : Wo0;
  } else {
    Aptr = det ? (Asc + (size_t)z * NE_)
               : (z == 0 ? Ao0 : (z == 1 ? Ao1 : Ao2));
    Wptr = det ? (Wsc + (size_t)z * WN_)
               : (z == 0 ? Wo0 : (z == 1 ? Wo1 : Wo2));
  }
  const char* Ag = (const char*)Aptr;
  const char* Wg = (const char*)Wptr;

  const int tid = threadIdx.x;
  const int lane = tid & 63, wid = tid >> 6;
  const int lg = lane >> 4, li = lane & 15;
  const int wr = wid >> 1, wc = wid & 1;
  const int m0 = blockIdx.x * 128, n0 = blockIdx.y * BN;

  const int lr = lane >> 3;
  const int swzb = ((lane & 7) * 16) ^ (lr << 4);

  auto issue = [&](int bi, int kt) {
    const int k0b = kt * 128;  // byte offset along K (64 elems)
#pragma unroll
    for (int c = 0; c < 4; ++c) {
      const int row = wid * 32 + c * 8 + lr;
      gl_lds16(Ag + (size_t)(m0 + row) * 2048 + k0b + swzb,
               &Al[bi][(wid * 32 + c * 8) * 64]);
    }
    if constexpr (BN == 128) {
#pragma unroll
      for (int c = 0; c < 4; ++c) {
        const int row = wid * 32 + c * 8 + lr;
        gl_lds16(Wg + (size_t)(n0 + row) * 2048 + k0b + swzb,
                 &Wl[bi][(wid * 32 + c * 8) * 64]);
      }
    } else {
#pragma unroll
      for (int c = 0; c < 2; ++c) {
        const int row = wid * 16 + c * 8 + lr;
        gl_lds16(Wg + (size_t)(n0 + row) * 2048 + k0b + swzb,
                 &Wl[bi][(wid * 16 + c * 8) * 64]);
      }
    }
  };

  constexpr int NF = BN / 32;
  f32x4 acc[4][NF];
#pragma unroll
  for (int m = 0; m < 4; ++m)
#pragma unroll
    for (int n = 0; n < NF; ++n) acc[m][n] = (f32x4){0.f, 0.f, 0.f, 0.f};

  issue(0, 0);

  for (int kt = 0; kt < 16; ++kt) {
    const int cur = kt & 1;
    if (kt < 15) {
      issue(cur ^ 1, kt + 1);
      // oldest LD loads (tile kt) must land; tile kt+1's stay in flight
      if constexpr (BN == 128)
        asm volatile("s_waitcnt vmcnt(8)" ::: "memory");
      else
        asm volatile("s_waitcnt vmcnt(6)" ::: "memory");
    } else {
      asm volatile("s_waitcnt vmcnt(0)" ::: "memory");
    }
    __builtin_amdgcn_s_barrier();
    asm volatile("" ::: "memory");

#pragma unroll
    for (int ks = 0; ks < 2; ++ks) {
      bf16x8 af[4], bw[NF];
#pragma unroll
      for (int m = 0; m < 4; ++m) {
        const int row = wr * 64 + m * 16 + li;
        af[m] = *(const bf16x8_ma*)((const char*)&Al[cur][0] + row * 128 +
                                    ((ks * 64 + lg * 16) ^ ((row & 7) << 4)));
      }
#pragma unroll
      for (int n = 0; n < NF; ++n) {
        const int row = wc * (BN / 2) + n * 16 + li;
        bw[n] = *(const bf16x8_ma*)((const char*)&Wl[cur][0] + row * 128 +
                                    ((ks * 64 + lg * 16) ^ ((row & 7) << 4)));
      }
#pragma unroll
      for (int m = 0; m < 4; ++m)
#pragma unroll
        for (int n = 0; n < NF; ++n)
          acc[m][n] = __builtin_amdgcn_mfma_f32_16x16x32_bf16(af[m], bw[n],
                                                              acc[m][n], 0, 0, 0);
    }

    asm volatile("" ::: "memory");
    __builtin_amdgcn_s_barrier();  // all waves done reading buf[cur]
  }

  const bool outf32 = OUT_DET ? det : false;
  const float zs = (!OUT_DET && z == 0) ? 0.125f : 1.0f;
#pragma unroll
  for (int m = 0; m < 4; ++m)
#pragma unroll
    for (int n = 0; n < NF; ++n)
#pragma unroll
      for (int r = 0; r < 4; ++r) {
        const int row = m0 + wr * 64 + m * 16 + lg * 4 + r;
        const int col = n0 + wc * (BN / 2) + n * 16 + li;
        const size_t idx = (size_t)row * D_ + col;
        const float v = acc[m][n][r] * zs;
        if (OUT_DET) {
          if (outf32)
            ((f32_ma*)Cb)[idx] = v;
          else
            ((u16_ma*)Cb)[idx] = rne1(v);
        } else {
          ((u16_ma*)((u16*)Cb + (size_t)z * NE_))[idx] = rne1(v);
        }
      }
}

// ---------------------------------------------------------------------------
// Flash attention: 32x32x16 MFMA swapped operands (R11-verified math),
// single-barrier K/V dbuf. K staged via gl_lds16 DMA with pre-swizzled
// source (layout == verified ds_write path); V reg-transposed as before.
// Tree-structured pmax/sum. K-DMA issued before V-loads so the vmcnt(0)
// guarding v_write retires it (in-order VMEM retirement).
// ---------------------------------------------------------------------------
__global__ __launch_bounds__(256) void attn3(
    const u16* __restrict__ Qg, const u16* __restrict__ Kg,
    const u16* __restrict__ Vg, u16* __restrict__ Og) {
  __shared__ u16 Kl[2][64 * 64];
  __shared__ u16 VTl[2][64 * 64];

  const int tid = threadIdx.x;
  const int wid = tid >> 6, lane = tid & 63;
  const int l31 = lane & 31;
  const int hi = lane >> 5;

  // T1 XCD swizzle (512 % 8 == 0)
  const int bid = blockIdx.x;
  const int swz = (bid & 7) * 64 + (bid >> 3);
  const int qb = swz & 15;
  const int h = (swz >> 4) & 15;
  const int b = swz >> 8;
  const size_t bbase = (size_t)b * S_ * D_;
  const int hoff = h * HD_;
  const int q0w = qb * 128 + wid * 32;

  // Q B-frags: bq[dblk] -> Q[q0w+l31][hoff + dblk*16 + hi*8 + e]
  bf16x8 bq[4];
  {
    const u16* qp = Qg + bbase + (size_t)(q0w + l31) * D_ + hoff + hi * 8;
#pragma unroll
    for (int dblk = 0; dblk < 4; ++dblk)
      bq[dblk] = *(const bf16x8_ma*)(qp + dblk * 16);
  }

  f32x16 o0, o1;
#pragma unroll
  for (int i = 0; i < 16; ++i) {
    o0[i] = 0.f;
    o1[i] = 0.f;
  }
  float mrun = -1e30f, lrun = 0.f;

  // K-DMA: per wave 2 calls cover rows [wid*16, wid*16+16), 8 rows/call.
  // Source pre-swizzled so LDS[row][c ^ ((row&7)<<4)] = K[row][c]
  // (identical layout to the verified ds_write staging).
  const int lr8 = lane >> 3;                          // 0..7 row within call
  const int ksz = ((lane & 7) * 16) ^ (lr8 << 4);     // swizzled src byte
  auto k_dma = [&](int bi, int kt) {
    const int key0 = kt * 64;
#pragma unroll
    for (int p = 0; p < 2; ++p) {
      const int row0 = wid * 16 + p * 8;
      const u16* srow = Kg + bbase + (size_t)(key0 + row0 + lr8) * D_ + hoff;
      gl_lds16((const char*)srow + ksz, &Kl[bi][row0 * 64]);
    }
  };

  const int vkr = lane;     // V-stage key row
  const int vd0 = wid * 8;  // V-stage d base (+32)
  v4u vr0, vr1;
  auto v_load = [&](int kt) {
    const int key0 = kt * 64;
    vr0 = *(const v4u_ma*)(Vg + bbase + (size_t)(key0 + vkr) * D_ + hoff + vd0);
    vr1 = *(const v4u_ma*)(Vg + bbase + (size_t)(key0 + vkr) * D_ + hoff + vd0 + 32);
  };
  auto v_write = [&](int bi) {
    char* Vb = (char*)&VTl[bi][0];
    union {
      v4u v;
      u16 e[8];
    } uu;
    uu.v = vr0;
#pragma unroll
    for (int j = 0; j < 8; ++j) {
      const int d = vd0 + j;
      *(u16*)(Vb + d * 128 + ((vkr * 2) ^ ((d & 7) << 4))) = uu.e[j];
    }
    uu.v = vr1;
#pragma unroll
    for (int j = 0; j < 8; ++j) {
      const int d = vd0 + 32 + j;
      *(u16*)(Vb + d * 128 + ((vkr * 2) ^ ((d & 7) << 4))) = uu.e[j];
    }
  };

  // prologue: tile 0. K-DMA first; v_write's vmcnt(0) (for vr regs) retires it.
  k_dma(0, 0);
  v_load(0);
  asm volatile("s_waitcnt vmcnt(0)" ::: "memory");
  v_write(0);

  const int swk = (l31 & 7) << 4;

  for (int kt = 0; kt < S_ / 64; ++kt) {
    __syncthreads();  // buf[kt&1] complete; prior-iter reads all retired
    const int cur = kt & 1;
    if (kt < S_ / 64 - 1) {
      k_dma(cur ^ 1, kt + 1);  // DMA into idle buffer (race-free post-barrier)
      v_load(kt + 1);          // V regs in flight across compute
    }

    const char* Kb = (const char*)&Kl[cur][0];
    const char* Vb = (const char*)&VTl[cur][0];

    // QK^T (Q pre-scaled by exact 0.125)
    f32x16 sT0, sT1;
#pragma unroll
    for (int i = 0; i < 16; ++i) {
      sT0[i] = 0.f;
      sT1[i] = 0.f;
    }
    __builtin_amdgcn_s_setprio(1);
#pragma unroll
    for (int dblk = 0; dblk < 4; ++dblk) {
      const int cb = (dblk * 32 + hi * 16);
      bf16x8 a0 = *(const bf16x8_ma*)(Kb + l31 * 128 + (cb ^ swk));
      bf16x8 a1 = *(const bf16x8_ma*)(Kb + (32 + l31) * 128 + (cb ^ swk));
      sT0 = __builtin_amdgcn_mfma_f32_32x32x16_bf16(a0, bq[dblk], sT0, 0, 0, 0);
      sT1 = __builtin_amdgcn_mfma_f32_32x32x16_bf16(a1, bq[dblk], sT1, 0, 0, 0);
    }
    __builtin_amdgcn_s_setprio(0);

    // row max: depth-5 tree (was 33-deep serial chain)
    float t[16];
#pragma unroll
    for (int i = 0; i < 16; ++i) t[i] = fmaxf(sT0[i], sT1[i]);
#pragma unroll
    for (int s = 8; s; s >>= 1)
#pragma unroll
      for (int i = 0; i < s; ++i) t[i] = fmaxf(t[i], t[i + s]);
    float pmax = fmaxf(t[0], __shfl_xor(t[0], 32));
    // T13 defer-max (nats, thr 8)
    if (!__all(pmax - mrun <= 8.0f)) {
      const float mnew = fmaxf(mrun, pmax);
      const float al = __expf(mrun - mnew);
      mrun = mnew;
      lrun *= al;
      o0 *= al;
      o1 *= al;
    }

    // p = exp(s - m); raw RNE pack; tree sum
    u32 w[16];
    float ps[16];
#pragma unroll
    for (int kh = 0; kh < 2; ++kh)
#pragma unroll
      for (int g = 0; g < 4; ++g)
#pragma unroll
        for (int u = 0; u < 2; ++u) {
          const int r = g * 4 + 2 * u;
          const float pe = __expf((kh ? sT1[r] : sT0[r]) - mrun);
          const float po = __expf((kh ? sT1[r + 1] : sT0[r + 1]) - mrun);
          ps[kh * 8 + g * 2 + u] = pe + po;
          w[kh * 8 + g * 2 + u] = rne_pair(pe, po);
        }
#pragma unroll
    for (int s = 8; s; s >>= 1)
#pragma unroll
      for (int i = 0; i < s; ++i) ps[i] += ps[i + s];
    lrun += ps[0] + __shfl_xor(ps[0], 32);

    // P B-frags via R8-verified shfl pair exchange
    bf16x8 pf[4];
#pragma unroll
    for (int km = 0; km < 4; ++km) {
      const int a = 4 * km;
      const u32 s0 = hi ? w[a] : w[a + 2];
      const u32 s1 = hi ? w[a + 1] : w[a + 3];
      const u32 r0 = (u32)__shfl_xor((int)s0, 32);
      const u32 r1 = (u32)__shfl_xor((int)s1, 32);
      union {
        u32 d[4];
        bf16x8 v;
      } uu;
      uu.d[0] = hi ? r0 : w[a];
      uu.d[1] = hi ? r1 : w[a + 1];
      uu.d[2] = hi ? w[a + 2] : r0;
      uu.d[3] = hi ? w[a + 3] : r1;
      pf[km] = uu.v;
    }

    // PV: O^T += V^T P^T
    __builtin_amdgcn_s_setprio(1);
#pragma unroll
    for (int km = 0; km < 4; ++km) {
      const int cb = (km * 32 + hi * 16);
      bf16x8 v0 = *(const bf16x8_ma*)(Vb + l31 * 128 + (cb ^ swk));
      bf16x8 v1 = *(const bf16x8_ma*)(Vb + (32 + l31) * 128 + (cb ^ swk));
      o0 = __builtin_amdgcn_mfma_f32_32x32x16_bf16(v0, pf[km], o0, 0, 0, 0);
      o1 = __builtin_amdgcn_mfma_f32_32x32x16_bf16(v1, pf[km], o1, 0, 0, 0);
    }
    __builtin_amdgcn_s_setprio(0);

    if (kt < S_ / 64 - 1) {
      // vmcnt(0): retires V-loads(kt+1) AND (in-order) K-DMA(kt+1)
      asm volatile("s_waitcnt vmcnt(0)" ::: "memory");
      v_write(cur ^ 1);
    }
  }

  // epilogue: lane holds O[q=q0w+l31][d=(r&3)+8*(r>>2)+4*hi (+32)]
  const float inv = 1.f / lrun;
  u16* orow = Og + bbase + (size_t)(q0w + l31) * D_ + hoff;
#pragma unroll
  for (int r = 0; r < 16; ++r) {
    const int d0 = (r & 3) + 8 * (r >> 2) + 4 * hi;
    orow[d0] = rne1(o0[r] * inv);
    orow[d0 + 32] = rne1(o1[r] * inv);
  }
}

// ---------------------------------------------------------------------------
// R5 golden slow path — fallback for small-ws worlds.
// ---------------------------------------------------------------------------
template <bool A_SCR, bool SCR_F32, bool OUT_FINAL>
__global__ __launch_bounds__(256) void proj_slow(
    const void* __restrict__ Ag, const u16* __restrict__ Wg,
    void* __restrict__ Cg) {
  const bool det = detect_f32(Wg);
  const bool a_f32 = A_SCR ? SCR_F32 : det;
  const int m = blockIdx.x;
  const int n = blockIdx.y * 256 + threadIdx.x;
  const size_t arow = (size_t)m * D_;
  const size_t wrow = (size_t)n * D_;
  float acc = 0.f;
  for (int k = 0; k < D_; ++k) {
    float a = a_f32 ? ((const f32_ma*)Ag)[arow + k]
                    : bf2f(((const u16_ma*)Ag)[arow + k]);
    float w = det ? ((const f32_ma*)Wg)[wrow + k]
                  : bf2f(((const u16_ma*)Wg)[wrow + k]);
    acc += a * w;
  }
  const size_t ci = (size_t)m * D_ + n;
  const bool c_f32 = OUT_FINAL ? det : SCR_F32;
  if (c_f32)
    ((f32_ma*)Cg)[ci] = acc;
  else
    ((u16_ma*)Cg)[ci] = f2bf(acc);
}

template <bool SCR_F32>
__global__ __launch_bounds__(256) void attn_slow(
    const void* __restrict__ Qg, const void* __restrict__ Kg,
    const void* __restrict__ Vg, void* __restrict__ Cg) {
  const int tid = threadIdx.x;
  const int qblk = blockIdx.x & 7;
  const int h = (blockIdx.x >> 3) & 15;
  const int b = blockIdx.x >> 7;
  const int q = qblk * 256 + tid;
  const size_t base = (size_t)b * S_ * D_;
  const int hoff = h * HD_;
  float qv[64];
  {
    const size_t qrow = base + (size_t)q * D_ + hoff;
    for (int d = 0; d < 64; ++d)
      qv[d] = SCR_F32 ? ((const f32_ma*)Qg)[qrow + d]
                      : bf2f(((const u16_ma*)Qg)[qrow + d]);
  }
  float o[64];
  for (int d = 0; d < 64; ++d) o[d] = 0.f;
  float m = -1e30f, l = 0.f;
  for (int key = 0; key < S_; ++key) {
    const size_t krow = base + (size_t)key * D_ + hoff;
    float s = 0.f;
    for (int d = 0; d < 64; ++d) {
      float kx = SCR_F32 ? ((const f32_ma*)Kg)[krow + d]
                         : bf2f(((const u16_ma*)Kg)[krow + d]);
      s += qv[d] * kx;
    }
    s *= 0.125f;
    float mn = fmaxf(m, s);
    float al = expf(m - mn);
    float pe = expf(s - mn);
    m = mn;
    l = l * al + pe;
    for (int d = 0; d < 64; ++d) {
      float vx = SCR_F32 ? ((const f32_ma*)Vg)[krow + d]
                         : bf2f(((const u16_ma*)Vg)[krow + d]);
      o[d] = o[d] * al + pe * vx;
    }
  }
  const float il = 1.f / l;
  const size_t crow = base + (size_t)q * D_ + hoff;
  for (int d = 0; d < 64; ++d) {
    if (SCR_F32)
      ((f32_ma*)Cg)[crow + d] = o[d] * il;
    else
      ((u16_ma*)Cg)[crow + d] = f2bf(o[d] * il);
  }
}

extern "C" void kernel_launch(void* const* d_in, const int* in_sizes, int n_in,
                              void* d_out, int out_size, void* d_ws,
                              size_t ws_size, hipStream_t stream) {
  const u16* Wdet = (const u16*)d_in[3];  // pristine Wq for device detect
  dim3 blk(256);

  // Host-side dtype dispatch: in_sizes[0] as BYTES discriminates the worlds.
  // bf16 bytes = 2*NE, fp32 bytes = 4*NE; anything else (e.g. element
  // counts) -> mode 2 (device-detect fallback, R5-R12 verified path).
  int mode = 2;
  if (n_in >= 7 && in_sizes) {
    if (in_sizes[0] == (int)((size_t)NE_ * 2)) mode = 0;       // bf16
    else if (in_sizes[0] == (int)((size_t)NE_ * 4)) mode = 1;  // fp32
  }

  if (ws_size >= (size_t)4 * NE_ * sizeof(float)) {
    u16* Qi = (u16*)d_ws;
    u16* Wc = Qi + (size_t)3 * NE_;
    u16* Qp = Wc + (size_t)4 * WN_;
    u16* Xp = Qp + (size_t)3 * NE_;

    if (mode != 0) {
      convert_bf16<<<dim3(2048, 7), blk, 0, stream>>>(
          d_in[0], d_in[1], d_in[2], d_in[3], d_in[4], d_in[5], d_in[6], Qi,
          Wc, Wdet, mode);
    }
    proj_g<128, false><<<dim3(32, 8, 3), blk, 0, stream>>>(
        Qi, Wc, Qp, Wdet, (const u16*)d_in[0], (const u16*)d_in[1],
        (const u16*)d_in[2], (const u16*)d_in[3], (const u16*)d_in[4],
        (const u16*)d_in[5], mode);
    attn3<<<dim3(512), blk, 0, stream>>>(Qp, Qp + NE_, Qp + (size_t)2 * NE_, Xp);
    proj_g<64, true><<<dim3(32, 16, 1), blk, 0, stream>>>(
        Xp, Wc + (size_t)3 * WN_, d_out, Wdet, nullptr, nullptr, nullptr,
        (const u16*)d_in[6], nullptr, nullptr, mode);
  } else {
    dim3 gproj(B_ * S_, D_ / 256);
    dim3 gattn(B_ * H_ * (S_ / 256));
    u16* Qp = (u16*)d_out;
    u16* Kp = (u16*)d_in[0];
    u16* Vp = (u16*)d_in[1];
    u16* Xp = (u16*)d_in[2];
    proj_slow<false, false, false><<<gproj, blk, 0, stream>>>(
        d_in[0], (const u16*)d_in[3], Qp);
    proj_slow<false, false, false><<<gproj, blk, 0, stream>>>(
        d_in[1], (const u16*)d_in[4], Kp);
    proj_slow<false, false, false><<<gproj, blk, 0, stream>>>(
        d_in[2], (const u16*)d_in[5], Vp);
    attn_slow<false><<<gattn, blk, 0, stream>>>(Qp, Kp, Vp, Xp);
    proj_slow<true, false, true><<<gproj, blk, 0, stream>>>(
        Xp, (const u16*)d_in[6], d_out);
  }
}